// Round 7
// baseline (173.408 us; speedup 1.0000x reference)
//
#include <hip/hip_runtime.h>
#include <math.h>

#define VV 8192
#define DD 768
#define NDMAX 256

typedef __attribute__((ext_vector_type(8))) short bf16x8;
typedef __attribute__((ext_vector_type(4))) float f32x4;

// RNE float -> bf16 bits
__device__ inline ushort f2bf(float f) {
    uint u = __float_as_uint(f);
    uint r = (u + 0x7fffu + ((u >> 16) & 1u)) >> 16;
    return (ushort)r;
}
__device__ inline float bf2f(ushort h) { return __uint_as_float(((uint)h) << 16); }

__device__ inline void gload16(const ushort* g, ushort* l) {
    __builtin_amdgcn_global_load_lds(
        (const __attribute__((address_space(1))) void*)g,
        (__attribute__((address_space(3))) void*)l, 16, 0, 0);
}
#define BAR() asm volatile("s_barrier" ::: "memory")
#define SCHED0() __builtin_amdgcn_sched_barrier(0)

// ---------------------------------------------------------------------------
// k_normpack: L2-normalize rows (fp64 norm accum) -> xh/xl (bf16 hi/lo split)
// + norms[r]. Also zeroes g and rc (replaces two memset dispatches).
// NOTE: fp32 x is NOT stored; downstream kernels recompute fp32(t/norm),
// which is bitwise identical to the old stored x -> mean path unchanged.
// ---------------------------------------------------------------------------
__global__ __launch_bounds__(256) void k_normpack(const float* __restrict__ t,
                                                  float* __restrict__ norms,
                                                  ushort* __restrict__ xh,
                                                  ushort* __restrict__ xl,
                                                  double* __restrict__ g,
                                                  float* __restrict__ rc) {
    int r = blockIdx.x;
    const float* tr = t + (size_t)r * DD;
    int tid = threadIdx.x;
    float v0 = tr[tid], v1 = tr[tid + 256], v2 = tr[tid + 512];
    double s = (double)v0 * v0 + (double)v1 * v1 + (double)v2 * v2;
#pragma unroll
    for (int o = 32; o > 0; o >>= 1) s += __shfl_down(s, o, 64);
    __shared__ double wsum[4];
    int lane = tid & 63, w = tid >> 6;
    if (lane == 0) wsum[w] = s;
    __syncthreads();
    double tot = wsum[0] + wsum[1] + wsum[2] + wsum[3];
    float norm = fmaxf((float)sqrt(tot), 1e-12f);
    if (tid == 0) {
        norms[r] = norm;
        rc[r] = 0.f;
        if (r < DD) g[r] = 0.0;
    }
    size_t base = (size_t)r * DD;
#pragma unroll
    for (int q = 0; q < 3; ++q) {
        int k = tid + q * 256;
        float v = (q == 0 ? v0 : (q == 1 ? v1 : v2)) / norm;
        ushort h = f2bf(v);
        xh[base + k] = h;
        xl[base + k] = f2bf(v - bf2f(h));
    }
}

// ---------------------------------------------------------------------------
// k_colsum: g[k] = sum over rows of fp32(t[r][k]/norm[r]), fp64 accum.
// ---------------------------------------------------------------------------
__global__ __launch_bounds__(256) void k_colsum(const float* __restrict__ t,
                                                const float* __restrict__ norms,
                                                double* __restrict__ g) {
    int k = threadIdx.x;
    int r0 = blockIdx.x * 32;
    double s0 = 0.0, s1 = 0.0, s2 = 0.0;
    for (int r = r0; r < r0 + 32; ++r) {
        const float* tr = t + (size_t)r * DD;
        float nrm = norms[r];
        s0 += (double)(tr[k] / nrm);
        s1 += (double)(tr[k + 256] / nrm);
        s2 += (double)(tr[k + 512] / nrm);
    }
    atomicAdd(&g[k], s0);
    atomicAdd(&g[k + 256], s1);
    atomicAdd(&g[k + 512], s2);
}

// ---------------------------------------------------------------------------
// k_mean: mnum[r] = x_r.g - x_r.x_r (fp64); dd[r] = x_r.x_r, with
// x = fp32(t/norm) recomputed on the fly (bitwise = old stored x).
// Exact mean path -- numerically deadly, do not approximate.
// ---------------------------------------------------------------------------
__global__ __launch_bounds__(256) void k_mean(const float* __restrict__ t,
                                              const float* __restrict__ norms,
                                              const double* __restrict__ g,
                                              double* __restrict__ mnum,
                                              double* __restrict__ dd) {
    int r = blockIdx.x * 4 + (threadIdx.x >> 6);
    int lane = threadIdx.x & 63;
    const float* tr = t + (size_t)r * DD;
    float nrm = norms[r];
    double xg = 0.0, xx = 0.0;
#pragma unroll
    for (int k = lane; k < DD; k += 64) {
        float xf = tr[k] / nrm;
        double xv = (double)xf;
        xg += xv * g[k];
        xx += xv * xv;
    }
#pragma unroll
    for (int o = 32; o > 0; o >>= 1) {
        xg += __shfl_down(xg, o, 64);
        xx += __shfl_down(xx, o, 64);
    }
    if (lane == 0) {
        mnum[r] = xg - xx;
        dd[r] = xx;
    }
}

// ---------------------------------------------------------------------------
// k_select: deterministic row-sorted compaction of "danger" rows
// (|mean_neg+eps| < 1e-5). Initializes dlist to -1 itself (single block).
// ---------------------------------------------------------------------------
__global__ __launch_bounds__(256) void k_select(const double* __restrict__ mnum,
                                                int* __restrict__ dlist) {
    __shared__ int cnts[256];
    int tid = threadIdx.x;
    dlist[tid] = -1;
    int r0 = tid * 32;
    int c = 0;
    for (int i = 0; i < 32; ++i) {
        double md = fabs(mnum[r0 + i] / 8191.0 + 1e-6);
        if (md < 1e-5) ++c;
    }
    cnts[tid] = c;
    __syncthreads();
    int pre = 0;
    for (int i = 0; i < tid; ++i) pre += cnts[i];
    for (int i = 0; i < 32; ++i) {
        int r = r0 + i;
        double md = fabs(mnum[r] / 8191.0 + 1e-6);
        if (md < 1e-5) {
            if (pre < NDMAX) dlist[pre] = r;
            ++pre;
        }
    }
}

// ---------------------------------------------------------------------------
// kloop12: 256x256 x K=768 MFMA loop, 12 K-tiles. ONE runtime barrier per
// K-tile (wave-slip: waves free-run within a tile so ds_read and MFMA from
// different waves overlap). All 8 prefetch loads for tile t+1 are issued at
// the top of tile t into the other buffer (disjoint from the read buffer ->
// race-free); single vmcnt(0) right before the tile-end barrier waits loads
// issued a full tile earlier. Static 4-chunk interleave kept via
// sched_barrier(0) (compile-time only) to cap register pressure.
// LDS k-half arrays [256][32] bf16, read-slot swizzle li4^((l15>>1)&3);
// staging via global_load_lds w=16 with pre-swizzled source, linear dest.
// ---------------------------------------------------------------------------
__device__ __forceinline__ void kloop12(const ushort* __restrict__ XA,
                                        const ushort* __restrict__ XB,
                                        int gA0, int gA1, int gB0, int gB1,
                                        int aoff, int boff, int ld0, int ld1,
                                        ushort* LDS, f32x4 (&acc)[8][4]) {
    // prologue: stage tile 0 into buf 0
    gload16(XA + gA0, LDS + ld0);              gload16(XA + gA1, LDS + ld1);
    gload16(XB + gB0, LDS + 16384 + ld0);      gload16(XB + gB1, LDS + 16384 + ld1);
    gload16(XA + gA0 + 32, LDS + 8192 + ld0);  gload16(XA + gA1 + 32, LDS + 8192 + ld1);
    gload16(XB + gB0 + 32, LDS + 24576 + ld0); gload16(XB + gB1 + 32, LDS + 24576 + ld1);
    asm volatile("s_waitcnt vmcnt(0)" ::: "memory");
    SCHED0(); BAR();

    for (int t = 0; t < 12; ++t) {
        const int cur = t & 1;
        ushort* Ak0 = LDS + cur * 32768;
        ushort* Ak1 = Ak0 + 8192;
        ushort* Bk0 = Ak0 + 16384;
        ushort* Bk1 = Ak0 + 24576;
        ushort* nA0 = LDS + (cur ^ 1) * 32768;
        ushort* nA1 = nA0 + 8192;
        ushort* nB0 = nA0 + 16384;
        ushort* nB1 = nA0 + 24576;
        const bool st = (t < 11);
        const int c1 = (t + 1) * 64;

        // issue ALL next-tile stages now (lands by the tile-end vmcnt(0))
        if (st) {
            gload16(XA + gA0 + c1, nA0 + ld0);       gload16(XA + gA1 + c1, nA0 + ld1);
            gload16(XB + gB0 + c1, nB0 + ld0);       gload16(XB + gB1 + c1, nB0 + ld1);
            gload16(XA + gA0 + c1 + 32, nA1 + ld0);  gload16(XA + gA1 + c1 + 32, nA1 + ld1);
            gload16(XB + gB0 + c1 + 32, nB1 + ld0);  gload16(XB + gB1 + c1 + 32, nB1 + ld1);
        }
        SCHED0();

        bf16x8 avA[4], avB[4], bv[4];
        // ---- chunk 1: A f0-3 ks0 x B ks0
#pragma unroll
        for (int f = 0; f < 4; ++f) avA[f] = *(const bf16x8*)(Ak0 + aoff + f * 512);
#pragma unroll
        for (int n = 0; n < 4; ++n) bv[n] = *(const bf16x8*)(Bk0 + boff + n * 512);
        __builtin_amdgcn_s_setprio(1);
#pragma unroll
        for (int f = 0; f < 4; ++f)
#pragma unroll
            for (int n = 0; n < 4; ++n)
                acc[f][n] = __builtin_amdgcn_mfma_f32_16x16x32_bf16(avA[f], bv[n], acc[f][n], 0, 0, 0);
        __builtin_amdgcn_s_setprio(0);
        SCHED0();
        // ---- chunk 2: A f4-7 ks0
#pragma unroll
        for (int f = 0; f < 4; ++f) avB[f] = *(const bf16x8*)(Ak0 + aoff + 2048 + f * 512);
        __builtin_amdgcn_s_setprio(1);
#pragma unroll
        for (int f = 0; f < 4; ++f)
#pragma unroll
            for (int n = 0; n < 4; ++n)
                acc[4 + f][n] = __builtin_amdgcn_mfma_f32_16x16x32_bf16(avB[f], bv[n], acc[4 + f][n], 0, 0, 0);
        __builtin_amdgcn_s_setprio(0);
        SCHED0();
        // ---- chunk 3: A f0-3 ks1 x B ks1
#pragma unroll
        for (int f = 0; f < 4; ++f) avA[f] = *(const bf16x8*)(Ak1 + aoff + f * 512);
#pragma unroll
        for (int n = 0; n < 4; ++n) bv[n] = *(const bf16x8*)(Bk1 + boff + n * 512);
        __builtin_amdgcn_s_setprio(1);
#pragma unroll
        for (int f = 0; f < 4; ++f)
#pragma unroll
            for (int n = 0; n < 4; ++n)
                acc[f][n] = __builtin_amdgcn_mfma_f32_16x16x32_bf16(avA[f], bv[n], acc[f][n], 0, 0, 0);
        __builtin_amdgcn_s_setprio(0);
        SCHED0();
        // ---- chunk 4: A f4-7 ks1
#pragma unroll
        for (int f = 0; f < 4; ++f) avB[f] = *(const bf16x8*)(Ak1 + aoff + 2048 + f * 512);
        __builtin_amdgcn_s_setprio(1);
#pragma unroll
        for (int f = 0; f < 4; ++f)
#pragma unroll
            for (int n = 0; n < 4; ++n)
                acc[4 + f][n] = __builtin_amdgcn_mfma_f32_16x16x32_bf16(avB[f], bv[n], acc[4 + f][n], 0, 0, 0);
        __builtin_amdgcn_s_setprio(0);

        // tile boundary: own stages landed + all waves done reading buf[cur]
        asm volatile("s_waitcnt vmcnt(0)" ::: "memory");
        SCHED0(); BAR();
    }
}

// ---------------------------------------------------------------------------
// k_cube: bf16 MFMA pass, all blocks ~uniform length.
//  - bids 0..95: strip-partial blocks (seg = bid/32 in {hh, lo.hi, hi.lo},
//    colchunk = bid%32): danger rows (gathered) x 256 cols, 12 K-tiles;
//    STORE partial S (f32) into Sb[seg] -- no cube, no atomics.
//  - bids 96..607: big 256^2 triangle tiles, 12 K-tiles (hh only),
//    XCD-bijective swizzle; cube + row/col sums via symmetry.
//  - bids 608..671: quarter tiles (128^2) of the last 16 triangle tiles.
// ---------------------------------------------------------------------------
__global__ __launch_bounds__(512, 2) void k_cube(const ushort* __restrict__ xh,
                                                 const ushort* __restrict__ xl,
                                                 const int* __restrict__ dlist,
                                                 float* __restrict__ Sb,
                                                 float* __restrict__ rc) {
    __shared__ ushort LDS[65536];  // 128 KiB

    const int bid = blockIdx.x;
    const int tid = threadIdx.x;
    const int lane = tid & 63;
    const int wid = tid >> 6;
    const int l15 = lane & 15, li4 = lane >> 4;
    const int swzrd = ((li4 ^ ((l15 >> 1) & 3)) << 3);

    if (bid >= 608) {
        // ---- quarter tile: 128x128, K=768 (hh only) ----
        const int qid = bid - 608;
        int wg = 512 + (qid >> 2), q = qid & 3;
        int bi = 0, rem = wg;
        while (rem >= 32 - bi) { rem -= 32 - bi; ++bi; }
        const int bj = bi + rem;
        const int gr = bi * 2 + (q >> 1), gc = bj * 2 + (q & 1);
        if (gc < gr) return;
        const int R0 = gr * 128, C0 = gc * 128;
        const int wm = wid >> 2, wn = wid & 3;  // per-wave 64x32
        const int aoff = (wm * 64 + l15) * 32 + swzrd;
        const int boff = (wn * 32 + l15) * 32 + swzrd;
        const int sl = ((tid & 3) ^ ((tid >> 3) & 3)) * 8;
        const int gA0 = (R0 + (tid >> 2)) * DD + sl;
        const int gB0 = (C0 + (tid >> 2)) * DD + sl;
        const int ld0 = tid * 8;

        f32x4 acc[4][2];
#pragma unroll
        for (int f = 0; f < 4; ++f)
#pragma unroll
            for (int n = 0; n < 2; ++n) acc[f][n] = (f32x4){0.f, 0.f, 0.f, 0.f};

        gload16(xh + gA0, LDS + ld0);
        gload16(xh + gB0, LDS + 8192 + ld0);
        gload16(xh + gA0 + 32, LDS + 4096 + ld0);
        gload16(xh + gB0 + 32, LDS + 12288 + ld0);
        asm volatile("s_waitcnt vmcnt(0)" ::: "memory");
        SCHED0(); BAR();

        for (int t = 0; t < 12; ++t) {
            const int cur = t & 1;
            ushort* A0 = LDS + cur * 16384;
            ushort* A1 = A0 + 4096;
            ushort* B0 = A0 + 8192;
            ushort* B1 = A0 + 12288;
            ushort* nA0 = LDS + (cur ^ 1) * 16384;
            const bool st = (t < 11);
            const int c1 = (t + 1) * 64;

            if (st) {
                gload16(xh + gA0 + c1, nA0 + ld0);
                gload16(xh + gB0 + c1, nA0 + 8192 + ld0);
                gload16(xh + gA0 + c1 + 32, nA0 + 4096 + ld0);
                gload16(xh + gB0 + c1 + 32, nA0 + 12288 + ld0);
            }
            SCHED0();
            bf16x8 av0[4], av1[4], bv0[2], bv1[2];
#pragma unroll
            for (int f = 0; f < 4; ++f) {
                av0[f] = *(const bf16x8*)(A0 + aoff + f * 512);
                av1[f] = *(const bf16x8*)(A1 + aoff + f * 512);
            }
#pragma unroll
            for (int n = 0; n < 2; ++n) {
                bv0[n] = *(const bf16x8*)(B0 + boff + n * 512);
                bv1[n] = *(const bf16x8*)(B1 + boff + n * 512);
            }
            __builtin_amdgcn_s_setprio(1);
#pragma unroll
            for (int f = 0; f < 4; ++f)
#pragma unroll
                for (int n = 0; n < 2; ++n)
                    acc[f][n] = __builtin_amdgcn_mfma_f32_16x16x32_bf16(av0[f], bv0[n], acc[f][n], 0, 0, 0);
#pragma unroll
            for (int f = 0; f < 4; ++f)
#pragma unroll
                for (int n = 0; n < 2; ++n)
                    acc[f][n] = __builtin_amdgcn_mfma_f32_16x16x32_bf16(av1[f], bv1[n], acc[f][n], 0, 0, 0);
            __builtin_amdgcn_s_setprio(0);
            asm volatile("s_waitcnt vmcnt(0)" ::: "memory");
            SCHED0(); BAR();
        }

        const bool dblk = (gr == gc);
        float rsum[4][4], csum[2];
#pragma unroll
        for (int n = 0; n < 2; ++n) csum[n] = 0.f;
#pragma unroll
        for (int f = 0; f < 4; ++f)
#pragma unroll
            for (int r = 0; r < 4; ++r) rsum[f][r] = 0.f;
#pragma unroll
        for (int f = 0; f < 4; ++f)
#pragma unroll
            for (int n = 0; n < 2; ++n)
#pragma unroll
                for (int r = 0; r < 4; ++r) {
                    float s = acc[f][n][r];
                    float c = s * s * s;
                    int ri = wm * 64 + f * 16 + li4 * 4 + r;
                    int cj = wn * 32 + n * 16 + l15;
                    if (dblk && ri == cj) c = 0.f;
                    rsum[f][r] += c;
                    csum[n] += c;
                }
#pragma unroll
        for (int o = 1; o < 16; o <<= 1)
#pragma unroll
            for (int f = 0; f < 4; ++f)
#pragma unroll
                for (int r = 0; r < 4; ++r)
                    rsum[f][r] += __shfl_xor(rsum[f][r], o, 64);
        if (l15 == 0) {
#pragma unroll
            for (int f = 0; f < 4; ++f)
#pragma unroll
                for (int r = 0; r < 4; ++r)
                    atomicAdd(&rc[R0 + wm * 64 + f * 16 + li4 * 4 + r], rsum[f][r]);
        }
        if (!dblk) {
#pragma unroll
            for (int o = 16; o < 64; o <<= 1)
#pragma unroll
                for (int n = 0; n < 2; ++n) csum[n] += __shfl_xor(csum[n], o, 64);
            if (li4 == 0) {
#pragma unroll
                for (int n = 0; n < 2; ++n)
                    atomicAdd(&rc[C0 + wn * 32 + n * 16 + l15], csum[n]);
            }
        }
        return;
    }

    // ---- shared 256x256 path: strip-partial (bid<96) or big tile ----
    const bool strip = (bid < 96);
    int bi = 0, bj = 0, seg = 0, cc = 0;
    if (strip) {
        seg = bid >> 5;
        cc = bid & 31;
    } else {
        const int idx = bid - 96;
        int wg = (idx & 7) * 64 + (idx >> 3);
        int rem = wg;
        while (rem >= 32 - bi) { rem -= 32 - bi; ++bi; }
        bj = bi + rem;
    }
    const int wm = wid >> 2, wn = wid & 3;  // 2M x 4N, per-wave 128x64
    const int aoff = (wm * 128 + l15) * 32 + swzrd;
    const int boff = (wn * 64 + l15) * 32 + swzrd;
    const int li0 = tid, li1 = tid + 512;
    const int sl0 = ((li0 & 3) ^ ((li0 >> 3) & 3)) * 8;
    const int sl1 = ((li1 & 3) ^ ((li1 >> 3) & 3)) * 8;
    int ar0, ar1, bt;
    const ushort *XA, *XB;
    if (strip) {
        ar0 = dlist[li0 >> 2]; if (ar0 < 0) ar0 = 0;
        ar1 = dlist[li1 >> 2]; if (ar1 < 0) ar1 = 0;
        bt = cc;
        XA = (seg == 1) ? xl : xh;
        XB = (seg == 2) ? xl : xh;
    } else {
        ar0 = bi * 256 + (li0 >> 2);
        ar1 = bi * 256 + (li1 >> 2);
        bt = bj;
        XA = xh; XB = xh;
    }
    const int gA0 = ar0 * DD + sl0;
    const int gA1 = ar1 * DD + sl1;
    const int gB0 = (bt * 256 + (li0 >> 2)) * DD + sl0;
    const int gB1 = (bt * 256 + (li1 >> 2)) * DD + sl1;
    const int ld0 = li0 * 8, ld1 = li1 * 8;

    f32x4 acc[8][4];
#pragma unroll
    for (int f = 0; f < 8; ++f)
#pragma unroll
        for (int n = 0; n < 4; ++n) acc[f][n] = (f32x4){0.f, 0.f, 0.f, 0.f};

    kloop12(XA, XB, gA0, gA1, gB0, gB1, aoff, boff, ld0, ld1, LDS, acc);

    if (strip) {
        // store partial S by danger slot (f32); finish pass cubes later
#pragma unroll
        for (int f = 0; f < 8; ++f)
#pragma unroll
            for (int n = 0; n < 4; ++n)
#pragma unroll
                for (int r = 0; r < 4; ++r) {
                    size_t slot = (size_t)(seg * 256 + wm * 128 + f * 16 + li4 * 4 + r);
                    Sb[(slot << 13) + cc * 256 + wn * 64 + n * 16 + l15] = acc[f][n][r];
                }
        return;
    }

    // big-tile epilogue: cube, skip diag, row + col (symmetry) sums
    const bool dblk = (bi == bj);
    float rsum[8][4], csum[4];
#pragma unroll
    for (int n = 0; n < 4; ++n) csum[n] = 0.f;
#pragma unroll
    for (int f = 0; f < 8; ++f)
#pragma unroll
        for (int r = 0; r < 4; ++r) rsum[f][r] = 0.f;
#pragma unroll
    for (int f = 0; f < 8; ++f)
#pragma unroll
        for (int n = 0; n < 4; ++n)
#pragma unroll
            for (int r = 0; r < 4; ++r) {
                float s = acc[f][n][r];
                float c = s * s * s;
                int ri = wm * 128 + f * 16 + li4 * 4 + r;
                int cj = wn * 64 + n * 16 + l15;
                if (dblk && ri == cj) c = 0.f;
                rsum[f][r] += c;
                csum[n] += c;
            }
#pragma unroll
    for (int o = 1; o < 16; o <<= 1)
#pragma unroll
        for (int f = 0; f < 8; ++f)
#pragma unroll
            for (int r = 0; r < 4; ++r)
                rsum[f][r] += __shfl_xor(rsum[f][r], o, 64);
    if (l15 == 0) {
#pragma unroll
        for (int f = 0; f < 8; ++f)
#pragma unroll
            for (int r = 0; r < 4; ++r)
                atomicAdd(&rc[bi * 256 + wm * 128 + f * 16 + li4 * 4 + r], rsum[f][r]);
    }
    if (!dblk) {
#pragma unroll
        for (int o = 16; o < 64; o <<= 1)
#pragma unroll
            for (int n = 0; n < 4; ++n) csum[n] += __shfl_xor(csum[n], o, 64);
        if (li4 == 0) {
#pragma unroll
            for (int n = 0; n < 4; ++n)
                atomicAdd(&rc[bj * 256 + wn * 64 + n * 16 + l15], csum[n]);
        }
    }
}

// ---------------------------------------------------------------------------
// k_cubefin: per danger slot, correction = sum_c [(s0+s1+s2)^3 - s0^3]
// (skip c == drow; s0 is bitwise-equal to the big pass's hh value, so the
// subtraction exactly removes the hh-cube already in rc).
// ---------------------------------------------------------------------------
__global__ __launch_bounds__(256) void k_cubefin(const float* __restrict__ Sb,
                                                 const int* __restrict__ dlist,
                                                 float* __restrict__ rc) {
    const int slot = blockIdx.x;
    const int drow = dlist[slot];
    if (drow < 0) return;
    const int tid = threadIdx.x;
    const float* s0p = Sb + ((size_t)slot << 13);
    const float* s1p = Sb + ((size_t)(256 + slot) << 13);
    const float* s2p = Sb + ((size_t)(512 + slot) << 13);
    float sum = 0.f;
    for (int c = tid; c < VV; c += 256) {
        float s0 = s0p[c];
        float sf = s0 + s1p[c] + s2p[c];
        float d = sf * sf * sf - s0 * s0 * s0;
        if (c == drow) d = 0.f;
        sum += d;
    }
    __shared__ float red[256];
    red[tid] = sum;
    __syncthreads();
    for (int o = 128; o > 0; o >>= 1) {
        if (tid < o) red[tid] += red[tid + o];
        __syncthreads();
    }
    if (tid == 0) atomicAdd(&rc[drow], red[0]);
}

// ---------------------------------------------------------------------------
// k_final: out = collapse + 0.2 * sum_i rc_i / (mnum_i/8191 + 1e-6)
// ---------------------------------------------------------------------------
__global__ __launch_bounds__(256) void k_final(const float* __restrict__ rc,
                                               const double* __restrict__ mnum,
                                               const double* __restrict__ dd,
                                               float* __restrict__ out) {
    int tid = threadIdx.x;
    double acc = 0.0, col = 0.0;
    for (int r = tid; r < VV; r += 256) {
        double m = mnum[r] / 8191.0 + 1e-6;
        acc += (double)rc[r] / m;
        double dm = dd[r] - 1.0;
        col += dm * dm;
    }
    __shared__ double sa[256], sc[256];
    sa[tid] = acc;
    sc[tid] = col;
    __syncthreads();
    for (int o = 128; o > 0; o >>= 1) {
        if (tid < o) {
            sa[tid] += sa[tid + o];
            sc[tid] += sc[tid + o];
        }
        __syncthreads();
    }
    if (tid == 0) out[0] = (float)(sc[0] + 0.2 * sa[0]);
}

// ---------------------------------------------------------------------------
extern "C" void kernel_launch(void* const* d_in, const int* in_sizes, int n_in,
                              void* d_out, int out_size, void* d_ws, size_t ws_size,
                              hipStream_t stream) {
    const float* t = (const float*)d_in[0];
    float* out = (float*)d_out;

    char* ws = (char*)d_ws;
    float* Sb = (float*)ws;  // 3*256*8192*4B = 24 MB (x buffer eliminated)
    size_t off = (size_t)VV * DD * sizeof(float);  // keep 25.2 MB region
    ushort* xh = (ushort*)(ws + off); off += (size_t)VV * DD * sizeof(ushort);
    ushort* xl = (ushort*)(ws + off); off += (size_t)VV * DD * sizeof(ushort);
    double* g = (double*)(ws + off);  off += DD * sizeof(double);
    double* mnum = (double*)(ws + off); off += VV * sizeof(double);
    double* dd = (double*)(ws + off);  off += VV * sizeof(double);
    float* rc = (float*)(ws + off);    off += VV * sizeof(float);
    int* dlist = (int*)(ws + off);     off += NDMAX * sizeof(int);
    float* norms = (float*)(ws + off); off += VV * sizeof(float);

    k_normpack<<<VV, 256, 0, stream>>>(t, norms, xh, xl, g, rc);
    k_colsum<<<256, 256, 0, stream>>>(t, norms, g);
    k_mean<<<VV / 4, 256, 0, stream>>>(t, norms, g, mnum, dd);
    k_select<<<1, 256, 0, stream>>>(mnum, dlist);
    k_cube<<<672, 512, 0, stream>>>(xh, xl, dlist, Sb, rc);
    k_cubefin<<<NDMAX, 256, 0, stream>>>(Sb, dlist, rc);
    k_final<<<1, 256, 0, stream>>>(rc, mnum, dd, out);
}